// Round 4
// baseline (671.071 us; speedup 1.0000x reference)
//
#include <hip/hip_runtime.h>
#include <stdint.h>

// SparseMoE gfx950, Round 4: fix workgroup->CU clustering for expert GEMMs.
// R3 evidence: GEMM2 = 299 TF == 32 CUs x 9.3 TF/CU per-CU peak; grid (8,32,32)
// with y<4 live put all live blocks on CU-slots (id/8)%32 in {0..3}. Fix:
// device-compacted live-tile list + 1-D contiguous grid. Kernel body unchanged.
typedef unsigned short ushort_t;
typedef __attribute__((ext_vector_type(8))) short short8;
typedef __attribute__((ext_vector_type(4))) float f32x4;

#define EMBED   1024
#define DFF     4096
#define NEXP    8
#define TOKENS  2048
#define SLOTS   4096
#define TMAX    40    // >= max Sum_e ceil(cnt_e/128) = 32+7 = 39

__device__ __forceinline__ ushort_t f2bf(float f) {
  unsigned u = __float_as_uint(f);
  u += 0x7FFFu + ((u >> 16) & 1u);   // RNE
  return (ushort_t)(u >> 16);
}
__device__ __forceinline__ float bf2f(ushort_t b) {
  return __uint_as_float(((unsigned)b) << 16);
}

// async 16B/lane global->LDS DMA. LDS dest wave-uniform; lane i lands at +16*i.
__device__ __forceinline__ void gl2lds16(const void* g, void* l) {
  typedef const __attribute__((address_space(1))) unsigned char* gp_t;
  typedef __attribute__((address_space(3))) unsigned char* lp_t;
  __builtin_amdgcn_global_load_lds((gp_t)(uintptr_t)g, (lp_t)(uintptr_t)l, 16, 0, 0);
}

__global__ void zero_small(int* counts, int* cursors) {
  int i = threadIdx.x;
  if (i < NEXP) { counts[i] = 0; cursors[i] = 0; }
}

// x [2048,1024] f32 -> Xs3 [2048,3072] bf16 : [xh | xl | xh]
__global__ void split_x3(const float* __restrict__ x, ushort_t* __restrict__ Xs) {
  int t = blockIdx.x;
  int d = threadIdx.x * 4;
  float4 v = *(const float4*)(x + (size_t)t * EMBED + d);
  ushort4 hi, lo;
  hi.x = f2bf(v.x); lo.x = f2bf(v.x - bf2f(hi.x));
  hi.y = f2bf(v.y); lo.y = f2bf(v.y - bf2f(hi.y));
  hi.z = f2bf(v.z); lo.z = f2bf(v.z - bf2f(hi.z));
  hi.w = f2bf(v.w); lo.w = f2bf(v.w - bf2f(hi.w));
  ushort_t* row = Xs + (size_t)t * 3072;
  *(ushort4*)(row + d)        = hi;
  *(ushort4*)(row + 1024 + d) = lo;
  *(ushort4*)(row + 2048 + d) = hi;
}

// transpose+convert: dst[n][dst_koff+k] = bf16( src[k][n] )  (lo: bf16 residual)
__global__ void transp_conv(const float* __restrict__ src, ushort_t* __restrict__ dst,
                            int src_ld, int dst_ld, long src_estride, long dst_estride,
                            int dst_koff, int lo)
{
  __shared__ float t[64][65];
  const float* s = src + (size_t)blockIdx.z * src_estride;
  ushort_t* d = dst + (size_t)blockIdx.z * dst_estride;
  int n0 = blockIdx.x * 64, k0 = blockIdx.y * 64;
  int tid = threadIdx.x;
  int kk = tid >> 4, nn = (tid & 15) * 4;
  #pragma unroll
  for (int it = 0; it < 4; it++) {
    float4 v = *(const float4*)(s + (size_t)(k0 + kk + it * 16) * src_ld + n0 + nn);
    t[kk + it * 16][nn]     = v.x;
    t[kk + it * 16][nn + 1] = v.y;
    t[kk + it * 16][nn + 2] = v.z;
    t[kk + it * 16][nn + 3] = v.w;
  }
  __syncthreads();
  int nn2 = tid >> 3, kk2 = (tid & 7) * 8;
  #pragma unroll
  for (int it = 0; it < 2; it++) {
    int n = nn2 + it * 32;
    union { ushort_t u[8]; uint4 v; } pk;
    #pragma unroll
    for (int j = 0; j < 8; j++) {
      float xv = t[kk2 + j][n];
      ushort_t hv = f2bf(xv);
      pk.u[j] = lo ? f2bf(xv - bf2f(hv)) : hv;
    }
    *(uint4*)(d + (size_t)(n0 + n) * dst_ld + dst_koff + k0 + kk2) = pk.v;
  }
}

// ---------------- MFMA GEMM ----------------
// 128x128 tile, BK=32, 4 waves 2x2, 4x4 mfma_16x16x32_bf16.
// LDS 128x32 unpadded, chunk-XOR swizzle slot(q,row)=q^((row>>1)&3).
// EXPERT: 1-D grid, bid = xi + NX*(kc + SPLITK*t); (e,y) from compacted tile list.
// OUTMODE 0: f32 store. 1: bf16 store. 2: atomicAdd(out[token][c], gate*v), bias on kc==0.
template<int BPATH, int OUTMODE, bool RELU, bool EXPERT, int SPLITK, int NX>
__global__ __launch_bounds__(256, 4)
void gemm_kernel(const ushort_t* __restrict__ A, const void* __restrict__ Bv,
                 const float* __restrict__ bias, void* __restrict__ Cout,
                 const float* __restrict__ slot_gate, const int* __restrict__ slot_token,
                 const int* __restrict__ off, const int* __restrict__ tile_e,
                 const int* __restrict__ tile_y, int M, int N, int K)
{
  __shared__ ushort_t As[128 * 32];
  __shared__ ushort_t Bs[128 * 32];

  int e = 0, kc = 0, row0, col0, m_base, m_cnt;
  if (EXPERT) {
    int bid  = blockIdx.x;
    int xi   = bid % NX;
    int rest = bid / NX;
    kc       = rest % SPLITK;
    int t    = rest / SPLITK;
    e = tile_e[t];
    if (e < 0) return;                    // padded tail, uniform exit
    row0   = tile_y[t] * 128;
    col0   = xi * 128;
    m_base = off[e];
    m_cnt  = off[e + 1] - m_base;
  } else {
    row0 = blockIdx.y * 128;
    col0 = blockIdx.x * 128;
    m_base = 0; m_cnt = M;
    if (row0 >= m_cnt) return;
  }
  const int Kc   = K / SPLITK;
  const int kbeg = kc * Kc;

  const int tid  = threadIdx.x;
  const int lane = tid & 63;
  const int wid  = tid >> 6;
  const int wm = wid & 1, wn = wid >> 1;

  // staging lane constants (DMA): lane i -> tile row base+(i>>2), slot i&3,
  // fetched global chunk = (i&3) ^ ((i>>3)&3)
  const int srow  = lane >> 2;
  const int schk8 = ((lane & 3) ^ ((lane >> 3) & 3)) * 8;

  const ushort_t* gA[2];
  ushort_t *ldsA[2], *ldsB[2];
  #pragma unroll
  for (int h = 0; h < 2; h++) {
    int r  = row0 + h * 64 + wid * 16 + srow;
    int rg = m_base + min(r, m_cnt - 1);     // clamp; OOB rows discarded in epilogue
    gA[h]   = A + (size_t)rg * K + kbeg + schk8;
    ldsA[h] = As + (h * 64 + wid * 16) * 32;
    ldsB[h] = Bs + (h * 64 + wid * 16) * 32;
  }
  const ushort_t* gB[2] = {nullptr, nullptr};
  const float* Bf = nullptr;
  if constexpr (BPATH == 0) {
    const ushort_t* Bt = (const ushort_t*)Bv + (EXPERT ? (size_t)e * N * K : 0);
    #pragma unroll
    for (int h = 0; h < 2; h++) {
      int n = col0 + h * 64 + wid * 16 + srow;
      gB[h] = Bt + (size_t)n * K + kbeg + schk8;
    }
  } else {
    Bf = (const float*)Bv + (EXPERT ? (size_t)e * (size_t)K * N : 0);
  }
  const int bn  = tid & 127;          // BPATH=1 staging col
  const int bc0 = (tid >> 7) << 1;    // BPATH=1 chunk pair

  f32x4 acc[4][4];
  #pragma unroll
  for (int i = 0; i < 4; i++)
    #pragma unroll
    for (int j = 0; j < 4; j++)
      acc[i][j] = (f32x4){0.f, 0.f, 0.f, 0.f};

  // fragment read constants
  const int q  = lane >> 4;
  const int rr = lane & 15;
  const int sw8 = (q ^ ((rr >> 1) & 3)) * 8;
  const int abase = (wm * 64 + rr) * 32 + sw8;
  const int bbase = (wn * 64 + rr) * 32 + sw8;

  const int nkt = Kc >> 5;
  for (int kt = 0; kt < nkt; kt++) {
    const int k0 = kt << 5;
    __syncthreads();
    #pragma unroll
    for (int h = 0; h < 2; h++) gl2lds16(gA[h] + k0, ldsA[h]);
    if constexpr (BPATH == 0) {
      #pragma unroll
      for (int h = 0; h < 2; h++) gl2lds16(gB[h] + k0, ldsB[h]);
    } else {
      #pragma unroll
      for (int ci = 0; ci < 2; ci++) {
        int c = bc0 + ci;
        union { ushort_t u[8]; uint4 v; } pk;
        #pragma unroll
        for (int j = 0; j < 8; j++)
          pk.u[j] = f2bf(Bf[(size_t)(kbeg + k0 + c * 8 + j) * N + col0 + bn]);
        int s = c ^ ((bn >> 1) & 3);
        *(uint4*)(Bs + bn * 32 + s * 8) = pk.v;
      }
    }
    __syncthreads();

    short8 af[4], bfr[4];
    #pragma unroll
    for (int i = 0; i < 4; i++) {
      af[i]  = *(const short8*)(As + abase + i * 512);
      bfr[i] = *(const short8*)(Bs + bbase + i * 512);
    }
    #pragma unroll
    for (int mt = 0; mt < 4; mt++)
      #pragma unroll
      for (int nt = 0; nt < 4; nt++)
        acc[mt][nt] = __builtin_amdgcn_mfma_f32_16x16x32_bf16(af[mt], bfr[nt], acc[mt][nt], 0, 0, 0);
  }

  // epilogue. C/D layout: col=lane&15, row=(lane>>4)*4+i  (m89-verified)
  const float* biasp = bias + (EXPERT ? (size_t)e * N : 0);
  float bv[4];
  #pragma unroll
  for (int nt = 0; nt < 4; nt++)
    bv[nt] = biasp[col0 + wn * 64 + nt * 16 + rr];
  const float bscale = (SPLITK == 1 || kc == 0) ? 1.f : 0.f;

  #pragma unroll
  for (int mt = 0; mt < 4; mt++) {
    #pragma unroll
    for (int i = 0; i < 4; i++) {
      int r_loc = row0 + wm * 64 + mt * 16 + q * 4 + i;
      if (r_loc < m_cnt) {
        int slot = m_base + r_loc;
        float g = 1.f; int tok = 0;
        if (OUTMODE == 2) { g = slot_gate[slot]; tok = slot_token[slot]; }
        #pragma unroll
        for (int nt = 0; nt < 4; nt++) {
          float v = acc[mt][nt][i] + bscale * bv[nt];
          if (RELU) v = fmaxf(v, 0.f);
          int c = col0 + wn * 64 + nt * 16 + rr;
          if (OUTMODE == 0)      ((float*)Cout)[(size_t)slot * N + c]    = v;
          else if (OUTMODE == 1) ((ushort_t*)Cout)[(size_t)slot * N + c] = f2bf(v);
          else atomicAdd(&((float*)Cout)[(size_t)tok * N + c], g * v);
        }
      }
    }
  }
}

// score = h @ rw2 + rb2 (fp32), then top-2 + softmax gates + expert counts.
__global__ void router_score(const float* __restrict__ h, const float* __restrict__ rw2,
                             const float* __restrict__ rb2, int* __restrict__ topi,
                             float* __restrict__ gates, int* __restrict__ counts)
{
  int t = blockIdx.x * 4 + (threadIdx.x >> 6);
  if (t >= TOKENS) return;
  int lane = threadIdx.x & 63;
  const float* hr = h + (size_t)t * DFF;
  float acc[8] = {0,0,0,0,0,0,0,0};
  for (int j = lane; j < DFF; j += 64) {
    float hv = hr[j];
    const float4* w = (const float4*)(rw2 + (size_t)j * 8);
    float4 w0 = w[0], w1 = w[1];
    acc[0] += hv * w0.x; acc[1] += hv * w0.y; acc[2] += hv * w0.z; acc[3] += hv * w0.w;
    acc[4] += hv * w1.x; acc[5] += hv * w1.y; acc[6] += hv * w1.z; acc[7] += hv * w1.w;
  }
  #pragma unroll
  for (int e = 0; e < 8; e++)
    for (int o = 32; o > 0; o >>= 1)
      acc[e] += __shfl_down(acc[e], o);
  if (lane == 0) {
    float s[8];
    #pragma unroll
    for (int e = 0; e < 8; e++) s[e] = acc[e] + rb2[e];
    int i0 = 0;
    #pragma unroll
    for (int e = 1; e < 8; e++) if (s[e] > s[i0]) i0 = e;   // ties -> lower idx (jax)
    int i1 = (i0 == 0) ? 1 : 0;
    #pragma unroll
    for (int e = 0; e < 8; e++) if (e != i0 && s[e] > s[i1]) i1 = e;
    float ex = __expf(s[i1] - s[i0]);
    float g0 = 1.f / (1.f + ex);
    float g1 = ex / (1.f + ex);
    topi[t * 2] = i0; topi[t * 2 + 1] = i1;
    gates[t * 2] = g0; gates[t * 2 + 1] = g1;
    atomicAdd(&counts[i0], 1);
    atomicAdd(&counts[i1], 1);
  }
}

// offsets + compacted live-tile list (tile index -> (expert, y-block))
__global__ void prefix_off(const int* __restrict__ counts, int* __restrict__ off,
                           int* __restrict__ tile_e, int* __restrict__ tile_y)
{
  if (threadIdx.x == 0) {
    int a = 0, t = 0;
    for (int e = 0; e < NEXP; e++) {
      off[e] = a;
      int c = counts[e]; a += c;
      int ty = (c + 127) >> 7;
      for (int y = 0; y < ty; y++) { tile_e[t] = e; tile_y[t] = y; t++; }
    }
    off[NEXP] = a;
    for (; t < TMAX; t++) { tile_e[t] = -1; tile_y[t] = 0; }
  }
}

__global__ void assign_slots(const int* __restrict__ topi, const float* __restrict__ gates,
                             const int* __restrict__ off, int* __restrict__ cursors,
                             int* __restrict__ slot_token, float* __restrict__ slot_gate)
{
  int t = blockIdx.x * blockDim.x + threadIdx.x;
  if (t >= TOKENS) return;
  #pragma unroll
  for (int k = 0; k < 2; k++) {
    int e = topi[t * 2 + k];
    int p = atomicAdd(&cursors[e], 1);
    int s = off[e] + p;
    slot_token[s] = t;
    slot_gate[s]  = gates[t * 2 + k];
  }
}

__global__ void gather_x(const float* __restrict__ x, const int* __restrict__ slot_token,
                         ushort_t* __restrict__ Xg)
{
  int s = blockIdx.x;
  int t = slot_token[s];
  int d = threadIdx.x * 4;
  float4 v = *(const float4*)(x + (size_t)t * EMBED + d);
  ushort4 o;
  o.x = f2bf(v.x); o.y = f2bf(v.y); o.z = f2bf(v.z); o.w = f2bf(v.w);
  *(ushort4*)(Xg + (size_t)s * EMBED + d) = o;
}

extern "C" void kernel_launch(void* const* d_in, const int* in_sizes, int n_in,
                              void* d_out, int out_size, void* d_ws, size_t ws_size,
                              hipStream_t stream)
{
  const float* x   = (const float*)d_in[0];
  const float* rw1 = (const float*)d_in[1];
  const float* rb1 = (const float*)d_in[2];
  const float* rw2 = (const float*)d_in[3];
  const float* rb2 = (const float*)d_in[4];
  const float* W1  = (const float*)d_in[5];
  const float* b1  = (const float*)d_in[6];
  const float* W2  = (const float*)d_in[7];
  const float* b2  = (const float*)d_in[8];
  float* out = (float*)d_out;
  char* ws = (char*)d_ws;

  const size_t SZ_RW1T = (size_t)4096 * 3072 * 2;
  const size_t SZ_XS3  = (size_t)2048 * 3072 * 2;
  const size_t SZ_WT   = (size_t)NEXP * 4096 * 1024 * 2;
  const size_t SZ_XG   = (size_t)SLOTS * EMBED * 2;
  const size_t SZ_H    = (size_t)SLOTS * DFF * 2;
  const size_t SZ_SMALL = 131072;
  const size_t NEED_A  = SZ_WT + SZ_XG + SZ_H + SZ_SMALL;
  const bool layoutA = (ws_size >= NEED_A);

  ushort_t *RW1t, *Xs3, *Wt, *Xg, *Hs;
  char* ps;
  if (layoutA) {
    Wt   = (ushort_t*)ws;
    RW1t = (ushort_t*)ws;
    Xs3  = (ushort_t*)(ws + SZ_RW1T);
    Xg   = (ushort_t*)(ws + SZ_WT);
    Hs   = (ushort_t*)(ws + SZ_WT + SZ_XG);
    ps   = ws + SZ_WT + SZ_XG + SZ_H;
  } else {
    Wt   = nullptr;
    RW1t = (ushort_t*)ws;
    Xs3  = (ushort_t*)(ws + SZ_RW1T);
    Xg   = (ushort_t*)(ws + SZ_RW1T + SZ_XS3);
    Hs   = (ushort_t*)(ws + SZ_RW1T + SZ_XS3 + SZ_XG);
    ps   = ws + SZ_RW1T + SZ_XS3 + SZ_XG + SZ_H;
  }
  float* h = (float*)Hs;                  // h aliases Hs (disjoint lifetimes)
  int*   topi       = (int*)ps;    ps += TOKENS * 2 * 4;
  float* gates      = (float*)ps;  ps += TOKENS * 2 * 4;
  int*   slot_token = (int*)ps;    ps += SLOTS * 4;
  float* slot_gate  = (float*)ps;  ps += SLOTS * 4;
  int*   counts     = (int*)ps;    ps += 256;
  int*   cursors    = (int*)ps;    ps += 256;
  int*   off        = (int*)ps;    ps += 256;
  int*   tile_e     = (int*)ps;    ps += 256;
  int*   tile_y     = (int*)ps;    ps += 256;

  hipMemsetAsync(d_out, 0, (size_t)TOKENS * EMBED * 4, stream);
  zero_small<<<1, 64, 0, stream>>>(counts, cursors);
  split_x3<<<TOKENS, 256, 0, stream>>>(x, Xs3);

  // RW1t [n=4096][k'=3072] = [wh | wh | wl] transposed from rw1 [1024][4096]
  transp_conv<<<dim3(64, 16, 1), 256, 0, stream>>>(rw1, RW1t, DFF, 3072, 0, 0, 0,    0);
  transp_conv<<<dim3(64, 16, 1), 256, 0, stream>>>(rw1, RW1t, DFF, 3072, 0, 0, 1024, 0);
  transp_conv<<<dim3(64, 16, 1), 256, 0, stream>>>(rw1, RW1t, DFF, 3072, 0, 0, 2048, 1);

  // Router: h = relu(Xs3 @ RW1t^T + rb1), fp32, K=3072
  gemm_kernel<0, 0, true, false, 1, 32>
      <<<dim3(32, 16, 1), 256, 0, stream>>>(Xs3, RW1t, rb1, h, nullptr, nullptr,
                                            nullptr, nullptr, nullptr, TOKENS, DFF, 3072);
  router_score<<<512, 256, 0, stream>>>(h, rw2, rb2, topi, gates, counts);
  prefix_off  <<<1, 64, 0, stream>>>(counts, off, tile_e, tile_y);
  assign_slots<<<8, 256, 0, stream>>>(topi, gates, off, cursors, slot_token, slot_gate);
  gather_x    <<<SLOTS, 256, 0, stream>>>(x, slot_token, Xg);

  if (layoutA) {
    // W1t [e][n=4096][k=1024]
    transp_conv<<<dim3(64, 16, NEXP), 256, 0, stream>>>(
        W1, Wt, DFF, EMBED, (long)EMBED * DFF, (long)DFF * EMBED, 0, 0);
    gemm_kernel<0, 1, true, true, 1, 32>
        <<<dim3(32 * TMAX, 1, 1), 256, 0, stream>>>(Xg, Wt, b1, Hs,
            nullptr, nullptr, off, tile_e, tile_y, 0, DFF, EMBED);
    // W2t [e][n=1024][k=4096]
    transp_conv<<<dim3(16, 64, NEXP), 256, 0, stream>>>(
        W2, Wt, EMBED, DFF, (long)DFF * EMBED, (long)EMBED * DFF, 0, 0);
    gemm_kernel<0, 2, false, true, 4, 8>
        <<<dim3(8 * 4 * TMAX, 1, 1), 256, 0, stream>>>(Hs, Wt, b2, out,
            slot_gate, slot_token, off, tile_e, tile_y, 0, EMBED, DFF);
  } else {
    gemm_kernel<1, 1, true, true, 1, 32>
        <<<dim3(32 * TMAX, 1, 1), 256, 0, stream>>>(Xg, W1, b1, Hs,
            nullptr, nullptr, off, tile_e, tile_y, 0, DFF, EMBED);
    gemm_kernel<1, 2, false, true, 4, 8>
        <<<dim3(8 * 4 * TMAX, 1, 1), 256, 0, stream>>>(Hs, W2, b2, out,
            slot_gate, slot_token, off, tile_e, tile_y, 0, EMBED, DFF);
  }
}

// Round 5
// 625.686 us; speedup vs baseline: 1.0725x; 1.0725x over previous
//
#include <hip/hip_runtime.h>
#include <stdint.h>

// SparseMoE gfx950, Round 5.
// R4 evidence: GEMM2 atomics = 134 MB HBM RMW (WRITE=67MB exactly = #atomics*4B),
// occupancy fix was neutral -> shared-resource bound. This round:
//  (1) GEMM2: SPLITK=2 partial stores (no atomics) + combine kernel.
//  (2) Expert GEMMs stage fp32 W1/W2 directly (BPATH=1) -> W transposes deleted.
typedef unsigned short ushort_t;
typedef __attribute__((ext_vector_type(8))) short short8;
typedef __attribute__((ext_vector_type(4))) float f32x4;

#define EMBED   1024
#define DFF     4096
#define NEXP    8
#define TOKENS  2048
#define SLOTS   4096
#define TMAX    40    // >= max Sum_e ceil(cnt_e/128) = 32+7 = 39

__device__ __forceinline__ ushort_t f2bf(float f) {
  unsigned u = __float_as_uint(f);
  u += 0x7FFFu + ((u >> 16) & 1u);   // RNE
  return (ushort_t)(u >> 16);
}
__device__ __forceinline__ float bf2f(ushort_t b) {
  return __uint_as_float(((unsigned)b) << 16);
}

// async 16B/lane global->LDS DMA. LDS dest wave-uniform; lane i lands at +16*i.
__device__ __forceinline__ void gl2lds16(const void* g, void* l) {
  typedef const __attribute__((address_space(1))) unsigned char* gp_t;
  typedef __attribute__((address_space(3))) unsigned char* lp_t;
  __builtin_amdgcn_global_load_lds((gp_t)(uintptr_t)g, (lp_t)(uintptr_t)l, 16, 0, 0);
}

__global__ void zero_small(int* counts, int* cursors) {
  int i = threadIdx.x;
  if (i < NEXP) { counts[i] = 0; cursors[i] = 0; }
}

// x [2048,1024] f32 -> Xs3 [2048,3072] bf16 : [xh | xl | xh]
__global__ void split_x3(const float* __restrict__ x, ushort_t* __restrict__ Xs) {
  int t = blockIdx.x;
  int d = threadIdx.x * 4;
  float4 v = *(const float4*)(x + (size_t)t * EMBED + d);
  ushort4 hi, lo;
  hi.x = f2bf(v.x); lo.x = f2bf(v.x - bf2f(hi.x));
  hi.y = f2bf(v.y); lo.y = f2bf(v.y - bf2f(hi.y));
  hi.z = f2bf(v.z); lo.z = f2bf(v.z - bf2f(hi.z));
  hi.w = f2bf(v.w); lo.w = f2bf(v.w - bf2f(hi.w));
  ushort_t* row = Xs + (size_t)t * 3072;
  *(ushort4*)(row + d)        = hi;
  *(ushort4*)(row + 1024 + d) = lo;
  *(ushort4*)(row + 2048 + d) = hi;
}

// transpose+convert: dst[n][dst_koff+k] = bf16( src[k][n] )  (lo: bf16 residual)
__global__ void transp_conv(const float* __restrict__ src, ushort_t* __restrict__ dst,
                            int src_ld, int dst_ld, long src_estride, long dst_estride,
                            int dst_koff, int lo)
{
  __shared__ float t[64][65];
  const float* s = src + (size_t)blockIdx.z * src_estride;
  ushort_t* d = dst + (size_t)blockIdx.z * dst_estride;
  int n0 = blockIdx.x * 64, k0 = blockIdx.y * 64;
  int tid = threadIdx.x;
  int kk = tid >> 4, nn = (tid & 15) * 4;
  #pragma unroll
  for (int it = 0; it < 4; it++) {
    float4 v = *(const float4*)(s + (size_t)(k0 + kk + it * 16) * src_ld + n0 + nn);
    t[kk + it * 16][nn]     = v.x;
    t[kk + it * 16][nn + 1] = v.y;
    t[kk + it * 16][nn + 2] = v.z;
    t[kk + it * 16][nn + 3] = v.w;
  }
  __syncthreads();
  int nn2 = tid >> 3, kk2 = (tid & 7) * 8;
  #pragma unroll
  for (int it = 0; it < 2; it++) {
    int n = nn2 + it * 32;
    union { ushort_t u[8]; uint4 v; } pk;
    #pragma unroll
    for (int j = 0; j < 8; j++) {
      float xv = t[kk2 + j][n];
      ushort_t hv = f2bf(xv);
      pk.u[j] = lo ? f2bf(xv - bf2f(hv)) : hv;
    }
    *(uint4*)(d + (size_t)(n0 + n) * dst_ld + dst_koff + k0 + kk2) = pk.v;
  }
}

// ---------------- MFMA GEMM ----------------
// 128x128 tile, BK=32, 4 waves 2x2, 4x4 mfma_16x16x32_bf16.
// LDS 128x32 unpadded, chunk-XOR swizzle slot(q,row)=q^((row>>1)&3).
// EXPERT: 1-D grid, bid = xi + NX*(kc + SPLITK*t); (e,y) from compacted tile list.
//   t-blocks sharing a B chunk are NX*SPLITK apart (mult of 8 -> same XCD under id%8).
// BPATH 0: B bf16 [n][k] via async DMA. 1: B fp32 [k][n], staged transpose+convert.
// OUTMODE 0: f32 store [slot][c]. 1: bf16 store [slot][c].
//         3: f32 gated partial store [kc][slot][c] (bias folded on kc==0).
template<int BPATH, int OUTMODE, bool RELU, bool EXPERT, int SPLITK, int NX>
__global__ __launch_bounds__(256, 4)
void gemm_kernel(const ushort_t* __restrict__ A, const void* __restrict__ Bv,
                 const float* __restrict__ bias, void* __restrict__ Cout,
                 const float* __restrict__ slot_gate,
                 const int* __restrict__ off, const int* __restrict__ tile_e,
                 const int* __restrict__ tile_y, int M, int N, int K)
{
  __shared__ ushort_t As[128 * 32];
  __shared__ ushort_t Bs[128 * 32];

  int e = 0, kc = 0, row0, col0, m_base, m_cnt;
  if (EXPERT) {
    int bid  = blockIdx.x;
    int xi   = bid % NX;
    int rest = bid / NX;
    kc       = rest % SPLITK;
    int t    = rest / SPLITK;
    e = tile_e[t];
    if (e < 0) return;                    // padded tail, uniform exit
    row0   = tile_y[t] * 128;
    col0   = xi * 128;
    m_base = off[e];
    m_cnt  = off[e + 1] - m_base;
  } else {
    row0 = blockIdx.y * 128;
    col0 = blockIdx.x * 128;
    m_base = 0; m_cnt = M;
    if (row0 >= m_cnt) return;
  }
  const int Kc   = K / SPLITK;
  const int kbeg = kc * Kc;

  const int tid  = threadIdx.x;
  const int lane = tid & 63;
  const int wid  = tid >> 6;
  const int wm = wid & 1, wn = wid >> 1;

  // staging lane constants (DMA): lane i -> tile row base+(i>>2), slot i&3,
  // fetched global chunk = (i&3) ^ ((i>>3)&3)
  const int srow  = lane >> 2;
  const int schk8 = ((lane & 3) ^ ((lane >> 3) & 3)) * 8;

  const ushort_t* gA[2];
  ushort_t *ldsA[2], *ldsB[2];
  #pragma unroll
  for (int h = 0; h < 2; h++) {
    int r  = row0 + h * 64 + wid * 16 + srow;
    int rg = m_base + min(r, m_cnt - 1);     // clamp; OOB rows discarded in epilogue
    gA[h]   = A + (size_t)rg * K + kbeg + schk8;
    ldsA[h] = As + (h * 64 + wid * 16) * 32;
    ldsB[h] = Bs + (h * 64 + wid * 16) * 32;
  }
  const ushort_t* gB[2] = {nullptr, nullptr};
  const float* Bf = nullptr;
  if constexpr (BPATH == 0) {
    const ushort_t* Bt = (const ushort_t*)Bv + (EXPERT ? (size_t)e * N * K : 0);
    #pragma unroll
    for (int h = 0; h < 2; h++) {
      int n = col0 + h * 64 + wid * 16 + srow;
      gB[h] = Bt + (size_t)n * K + kbeg + schk8;
    }
  } else {
    Bf = (const float*)Bv + (EXPERT ? (size_t)e * (size_t)K * N : 0);
  }
  const int bn  = tid & 127;          // BPATH=1 staging col
  const int bc0 = (tid >> 7) << 1;    // BPATH=1 chunk pair

  f32x4 acc[4][4];
  #pragma unroll
  for (int i = 0; i < 4; i++)
    #pragma unroll
    for (int j = 0; j < 4; j++)
      acc[i][j] = (f32x4){0.f, 0.f, 0.f, 0.f};

  // fragment read constants
  const int q  = lane >> 4;
  const int rr = lane & 15;
  const int sw8 = (q ^ ((rr >> 1) & 3)) * 8;
  const int abase = (wm * 64 + rr) * 32 + sw8;
  const int bbase = (wn * 64 + rr) * 32 + sw8;

  const int nkt = Kc >> 5;
  for (int kt = 0; kt < nkt; kt++) {
    const int k0 = kt << 5;
    __syncthreads();
    #pragma unroll
    for (int h = 0; h < 2; h++) gl2lds16(gA[h] + k0, ldsA[h]);
    if constexpr (BPATH == 0) {
      #pragma unroll
      for (int h = 0; h < 2; h++) gl2lds16(gB[h] + k0, ldsB[h]);
    } else {
      #pragma unroll
      for (int ci = 0; ci < 2; ci++) {
        int c = bc0 + ci;
        union { ushort_t u[8]; uint4 v; } pk;
        #pragma unroll
        for (int j = 0; j < 8; j++)
          pk.u[j] = f2bf(Bf[(size_t)(kbeg + k0 + c * 8 + j) * N + col0 + bn]);
        int s = c ^ ((bn >> 1) & 3);
        *(uint4*)(Bs + bn * 32 + s * 8) = pk.v;
      }
    }
    __syncthreads();

    short8 af[4], bfr[4];
    #pragma unroll
    for (int i = 0; i < 4; i++) {
      af[i]  = *(const short8*)(As + abase + i * 512);
      bfr[i] = *(const short8*)(Bs + bbase + i * 512);
    }
    #pragma unroll
    for (int mt = 0; mt < 4; mt++)
      #pragma unroll
      for (int nt = 0; nt < 4; nt++)
        acc[mt][nt] = __builtin_amdgcn_mfma_f32_16x16x32_bf16(af[mt], bfr[nt], acc[mt][nt], 0, 0, 0);
  }

  // epilogue. C/D layout: col=lane&15, row=(lane>>4)*4+i  (m89-verified)
  const float* biasp = bias + (EXPERT ? (size_t)e * N : 0);
  float bv[4];
  #pragma unroll
  for (int nt = 0; nt < 4; nt++)
    bv[nt] = biasp[col0 + wn * 64 + nt * 16 + rr];
  const float bscale = (SPLITK == 1 || kc == 0) ? 1.f : 0.f;

  #pragma unroll
  for (int mt = 0; mt < 4; mt++) {
    #pragma unroll
    for (int i = 0; i < 4; i++) {
      int r_loc = row0 + wm * 64 + mt * 16 + q * 4 + i;
      if (r_loc < m_cnt) {
        int slot = m_base + r_loc;
        float g = 1.f;
        if (OUTMODE == 3) g = slot_gate[slot];
        #pragma unroll
        for (int nt = 0; nt < 4; nt++) {
          float v = acc[mt][nt][i] + bscale * bv[nt];
          if (RELU) v = fmaxf(v, 0.f);
          int c = col0 + wn * 64 + nt * 16 + rr;
          if (OUTMODE == 0)      ((float*)Cout)[(size_t)slot * N + c]    = v;
          else if (OUTMODE == 1) ((ushort_t*)Cout)[(size_t)slot * N + c] = f2bf(v);
          else ((float*)Cout)[((size_t)kc * SLOTS + slot) * N + c] = g * v;
        }
      }
    }
  }
}

// score = h @ rw2 + rb2 (fp32), then top-2 + softmax gates + expert counts.
__global__ void router_score(const float* __restrict__ h, const float* __restrict__ rw2,
                             const float* __restrict__ rb2, int* __restrict__ topi,
                             float* __restrict__ gates, int* __restrict__ counts)
{
  int t = blockIdx.x * 4 + (threadIdx.x >> 6);
  if (t >= TOKENS) return;
  int lane = threadIdx.x & 63;
  const float* hr = h + (size_t)t * DFF;
  float acc[8] = {0,0,0,0,0,0,0,0};
  for (int j = lane; j < DFF; j += 64) {
    float hv = hr[j];
    const float4* w = (const float4*)(rw2 + (size_t)j * 8);
    float4 w0 = w[0], w1 = w[1];
    acc[0] += hv * w0.x; acc[1] += hv * w0.y; acc[2] += hv * w0.z; acc[3] += hv * w0.w;
    acc[4] += hv * w1.x; acc[5] += hv * w1.y; acc[6] += hv * w1.z; acc[7] += hv * w1.w;
  }
  #pragma unroll
  for (int e = 0; e < 8; e++)
    for (int o = 32; o > 0; o >>= 1)
      acc[e] += __shfl_down(acc[e], o);
  if (lane == 0) {
    float s[8];
    #pragma unroll
    for (int e = 0; e < 8; e++) s[e] = acc[e] + rb2[e];
    int i0 = 0;
    #pragma unroll
    for (int e = 1; e < 8; e++) if (s[e] > s[i0]) i0 = e;   // ties -> lower idx (jax)
    int i1 = (i0 == 0) ? 1 : 0;
    #pragma unroll
    for (int e = 0; e < 8; e++) if (e != i0 && s[e] > s[i1]) i1 = e;
    float ex = __expf(s[i1] - s[i0]);
    float g0 = 1.f / (1.f + ex);
    float g1 = ex / (1.f + ex);
    topi[t * 2] = i0; topi[t * 2 + 1] = i1;
    gates[t * 2] = g0; gates[t * 2 + 1] = g1;
    atomicAdd(&counts[i0], 1);
    atomicAdd(&counts[i1], 1);
  }
}

// offsets + compacted live-tile list (tile index -> (expert, y-block))
__global__ void prefix_off(const int* __restrict__ counts, int* __restrict__ off,
                           int* __restrict__ tile_e, int* __restrict__ tile_y)
{
  if (threadIdx.x == 0) {
    int a = 0, t = 0;
    for (int e = 0; e < NEXP; e++) {
      off[e] = a;
      int c = counts[e]; a += c;
      int ty = (c + 127) >> 7;
      for (int y = 0; y < ty; y++) { tile_e[t] = e; tile_y[t] = y; t++; }
    }
    off[NEXP] = a;
    for (; t < TMAX; t++) { tile_e[t] = -1; tile_y[t] = 0; }
  }
}

__global__ void assign_slots(const int* __restrict__ topi, const float* __restrict__ gates,
                             const int* __restrict__ off, int* __restrict__ cursors,
                             int* __restrict__ slot_token, float* __restrict__ slot_gate,
                             int* __restrict__ tok_slot)
{
  int t = blockIdx.x * blockDim.x + threadIdx.x;
  if (t >= TOKENS) return;
  #pragma unroll
  for (int k = 0; k < 2; k++) {
    int e = topi[t * 2 + k];
    int p = atomicAdd(&cursors[e], 1);
    int s = off[e] + p;
    slot_token[s] = t;
    slot_gate[s]  = gates[t * 2 + k];
    tok_slot[t * 2 + k] = s;
  }
}

__global__ void gather_x(const float* __restrict__ x, const int* __restrict__ slot_token,
                         ushort_t* __restrict__ Xg)
{
  int s = blockIdx.x;
  int t = slot_token[s];
  int d = threadIdx.x * 4;
  float4 v = *(const float4*)(x + (size_t)t * EMBED + d);
  ushort4 o;
  o.x = f2bf(v.x); o.y = f2bf(v.y); o.z = f2bf(v.z); o.w = f2bf(v.w);
  *(ushort4*)(Xg + (size_t)s * EMBED + d) = o;
}

// out[t] = sum over {2 slots} x {2 k-chunks} of gated partials (gate/bias folded)
__global__ void combine_out(const float* __restrict__ Ys, const int* __restrict__ tok_slot,
                            float* __restrict__ out)
{
  int t = blockIdx.x;
  int d = threadIdx.x * 4;
  int s0 = tok_slot[t * 2], s1 = tok_slot[t * 2 + 1];
  float4 a = *(const float4*)(Ys + (size_t)s0 * EMBED + d);
  float4 b = *(const float4*)(Ys + ((size_t)SLOTS + s0) * EMBED + d);
  float4 c = *(const float4*)(Ys + (size_t)s1 * EMBED + d);
  float4 e = *(const float4*)(Ys + ((size_t)SLOTS + s1) * EMBED + d);
  float4 o;
  o.x = (a.x + b.x) + (c.x + e.x);
  o.y = (a.y + b.y) + (c.y + e.y);
  o.z = (a.z + b.z) + (c.z + e.z);
  o.w = (a.w + b.w) + (c.w + e.w);
  *(float4*)(out + (size_t)t * EMBED + d) = o;
}

extern "C" void kernel_launch(void* const* d_in, const int* in_sizes, int n_in,
                              void* d_out, int out_size, void* d_ws, size_t ws_size,
                              hipStream_t stream)
{
  const float* x   = (const float*)d_in[0];
  const float* rw1 = (const float*)d_in[1];
  const float* rb1 = (const float*)d_in[2];
  const float* rw2 = (const float*)d_in[3];
  const float* rb2 = (const float*)d_in[4];
  const float* W1  = (const float*)d_in[5];
  const float* b1  = (const float*)d_in[6];
  const float* W2  = (const float*)d_in[7];
  const float* b2  = (const float*)d_in[8];
  float* out = (float*)d_out;
  char* ws = (char*)d_ws;

  // Single layout, ~80 MB (R3/R4 proved ws >= 109 MB):
  // [RW1t 25.2MB][Xs3 12.6MB][Xg 8.4MB][Hs/h 33.5MB][small]
  // Ys [2][4096][1024] f32 (33.5MB) aliases RW1t+Xs3 (dead after router GEMM).
  const size_t SZ_RW1T = (size_t)4096 * 3072 * 2;
  const size_t SZ_XS3  = (size_t)2048 * 3072 * 2;
  const size_t SZ_XG   = (size_t)SLOTS * EMBED * 2;
  const size_t SZ_H    = (size_t)SLOTS * DFF * 2;

  ushort_t* RW1t = (ushort_t*)ws;
  float*    Ys   = (float*)ws;                         // [2*SLOTS, 1024] f32
  ushort_t* Xs3  = (ushort_t*)(ws + SZ_RW1T);
  ushort_t* Xg   = (ushort_t*)(ws + SZ_RW1T + SZ_XS3);
  ushort_t* Hs   = (ushort_t*)(ws + SZ_RW1T + SZ_XS3 + SZ_XG);
  float*    h    = (float*)Hs;                         // h aliases Hs (disjoint lifetimes)
  char* ps = ws + SZ_RW1T + SZ_XS3 + SZ_XG + SZ_H;
  int*   topi       = (int*)ps;    ps += TOKENS * 2 * 4;
  float* gates      = (float*)ps;  ps += TOKENS * 2 * 4;
  int*   tok_slot   = (int*)ps;    ps += TOKENS * 2 * 4;
  int*   slot_token = (int*)ps;    ps += SLOTS * 4;
  float* slot_gate  = (float*)ps;  ps += SLOTS * 4;
  int*   counts     = (int*)ps;    ps += 256;
  int*   cursors    = (int*)ps;    ps += 256;
  int*   off        = (int*)ps;    ps += 256;
  int*   tile_e     = (int*)ps;    ps += 256;
  int*   tile_y     = (int*)ps;    ps += 256;

  zero_small<<<1, 64, 0, stream>>>(counts, cursors);
  split_x3<<<TOKENS, 256, 0, stream>>>(x, Xs3);

  // RW1t [n=4096][k'=3072] = [wh | wh | wl] transposed from rw1 [1024][4096]
  transp_conv<<<dim3(64, 16, 1), 256, 0, stream>>>(rw1, RW1t, DFF, 3072, 0, 0, 0,    0);
  transp_conv<<<dim3(64, 16, 1), 256, 0, stream>>>(rw1, RW1t, DFF, 3072, 0, 0, 1024, 0);
  transp_conv<<<dim3(64, 16, 1), 256, 0, stream>>>(rw1, RW1t, DFF, 3072, 0, 0, 2048, 1);

  // Router: h = relu(Xs3 @ RW1t^T + rb1), fp32, K=3072
  gemm_kernel<0, 0, true, false, 1, 32>
      <<<dim3(32, 16, 1), 256, 0, stream>>>(Xs3, RW1t, rb1, h, nullptr,
                                            nullptr, nullptr, nullptr, TOKENS, DFF, 3072);
  router_score<<<512, 256, 0, stream>>>(h, rw2, rb2, topi, gates, counts);
  prefix_off  <<<1, 64, 0, stream>>>(counts, off, tile_e, tile_y);
  assign_slots<<<8, 256, 0, stream>>>(topi, gates, off, cursors, slot_token, slot_gate, tok_slot);
  gather_x    <<<SLOTS, 256, 0, stream>>>(x, slot_token, Xg);

  // Expert GEMM1: Hs = relu(Xg @ W1[e] + b1[e]), bf16 out; W1 staged fp32->bf16 in-kernel
  gemm_kernel<1, 1, true, true, 1, 32>
      <<<dim3(32 * TMAX, 1, 1), 256, 0, stream>>>(Xg, W1, b1, Hs,
          nullptr, off, tile_e, tile_y, 0, DFF, EMBED);
  // Expert GEMM2: Ys[kc][slot] = gate*(Hs @ W2[e] kc-chunk + [kc==0]*b2[e]), fp32 partials
  gemm_kernel<1, 3, false, true, 2, 8>
      <<<dim3(8 * 2 * TMAX, 1, 1), 256, 0, stream>>>(Hs, W2, b2, Ys,
          slot_gate, off, tile_e, tile_y, 0, EMBED, DFF);

  combine_out<<<TOKENS, 256, 0, stream>>>(Ys, tok_slot, out);
}